// Round 10
// baseline (471.923 us; speedup 1.0000x reference)
//
#include <hip/hip_runtime.h>

// B=4, HT=WT=256, WS=8, NH=8, VD=128, HD=16, WH=WW=32
// 4096 windows x 64 tokens; per head: qk-dim 32 (16 value + 16 coord), v-dim 16.
//
// Register-resident design: Q^T/K^T/V computed via transposed-weight MFMAs so
// their D-fragments feed the S^T and PV MFMAs directly (k-permutation trick);
// only X (input), Y (pre-projection, overlays XV) and POS go through LDS.
// R5: biases folded into MFMA C-init; deferred softmax normalization; 0.25
//     scale folded into prepped Wq fragments.
// R6: per-ni attention streaming + per-ks X loads (unified-reg diet, target 3
//     blocks/CU); POS folded into S-MFMA C-init; masks under uniform branch;
//     no max-subtract (inputs bounded); phase-3 operand swap -> dwordx4 stores.

typedef __bf16 bf16_t;
typedef __bf16 bf16x4 __attribute__((ext_vector_type(4)));
typedef __bf16 bf16x8 __attribute__((ext_vector_type(8)));
typedef float f32x4 __attribute__((ext_vector_type(4)));

#define SMEM_BYTES 35840
// LDS: XV [64][136] bf16 @0 (17408, overlaid by Y after barrier 2)
//      XC [64][136] bf16 @17408 | POS [225] f32 @34816

// ws layout (bf16 elems), 98304 elems = 196608 bytes total:
//   head h (h<8): base h*10240, frags of 512:
//     [0..3]  WqvT A-frags (ks 0..3)  = 0.25*Wv[kin][((l&15)*8+h)*3+0]  (kin=ks*32+(l>>4)*8+j)
//     [4..7]  WkvT                     =      Wv[kin][((l&15)*8+h)*3+1]
//     [8..11] WqcT                     = 0.25*Wc[kin][((l&15)*8+h)*2+0]
//     [12..15]WkcT                     =      Wc[kin][((l&15)*8+h)*2+1]
//     [16..19]WvV  B-frags             =      Wv[kin][((l&15)*8+h)*3+2]
//   Wo frags: 81920 + (nt*4+ks)*512:   Wo[kin][nt*16+(l&15)]   (used as A in phase 3)
__global__ __launch_bounds__(512) void prep_weights_k(
    const float* __restrict__ Wv, const float* __restrict__ Wc,
    const float* __restrict__ Wo, bf16_t* __restrict__ wsW) {
  int g = blockIdx.x * 512 + threadIdx.x;   // 192*512 = 98304
  int frag = g >> 9, within = g & 511;
  int l = within >> 3, j = within & 7;
  int cc = l & 15;
  int kin_off = ((l >> 4) << 3) + j;
  float val;
  if (frag < 160) {
    int h = frag / 20, fi = frag % 20;
    int type = fi >> 2, ks = fi & 3;
    int kin = ks * 32 + kin_off;
    if (type == 0)      val = 0.25f * Wv[kin * 384 + (cc * 8 + h) * 3];
    else if (type == 1) val = Wv[kin * 384 + (cc * 8 + h) * 3 + 1];
    else if (type == 2) val = 0.25f * Wc[kin * 256 + (cc * 8 + h) * 2];
    else if (type == 3) val = Wc[kin * 256 + (cc * 8 + h) * 2 + 1];
    else                val = Wv[kin * 384 + (cc * 8 + h) * 3 + 2];
    wsW[g] = (bf16_t)val;
  } else {
    int f = frag - 160, nt = f >> 2, ks = f & 3;
    int kin = ks * 32 + kin_off;
    wsW[g] = (bf16_t)Wo[kin * 128 + nt * 16 + cc];
  }
}

__global__ __launch_bounds__(512, 6) void swin_fused_k(
    const float* __restrict__ gxv, const float* __restrict__ gxc,
    const float* __restrict__ bv, const float* __restrict__ bc,
    const float* __restrict__ pos_g, const float* __restrict__ bo,
    const bf16_t* __restrict__ wsW, float* __restrict__ out) {
  extern __shared__ char smem[];
  bf16_t* XV = (bf16_t*)(smem);
  bf16_t* XC = (bf16_t*)(smem + 17408);
  bf16_t* Y  = (bf16_t*)(smem);           // overlays XV after barrier 2
  float*  POS = (float*)(smem + 34816);

  const int tid = threadIdx.x;
  const int l = tid & 63;
  const int w = tid >> 6;          // wave id = head id
  const int col16 = l & 15;
  const int q = l >> 4;            // lane quad

  const int bid = blockIdx.x;
  const int b = bid >> 10;
  const int rem = bid & 1023;
  const int wy = rem >> 5, wx = rem & 31;
  const bool lastRow = (wy == 31), lastCol = (wx == 31);

  if (tid < 225) POS[tid] = pos_g[tid];

  const int h = w;

  // ---- stage rolled inputs -> LDS bf16 [64][136] ----
  {
    const int t = tid >> 3, qq = tid & 7;
    const int rs = ((wy << 3) + (t >> 3) + 4) & 255;
    const int cs = ((wx << 3) + (t & 7) + 4) & 255;
    const size_t base = ((size_t)b * 65536 + (size_t)rs * 256 + (size_t)cs) * 128;
    const float4* pv = (const float4*)(gxv + base);
    const float4* pc = (const float4*)(gxc + base);
#pragma unroll
    for (int i = 0; i < 4; ++i) {
      float4 a = pv[i * 8 + qq];
      bf16x4 pk; pk[0]=(bf16_t)a.x; pk[1]=(bf16_t)a.y; pk[2]=(bf16_t)a.z; pk[3]=(bf16_t)a.w;
      *(bf16x4*)(XV + t * 136 + (i * 8 + qq) * 4) = pk;
      float4 c = pc[i * 8 + qq];
      bf16x4 qk; qk[0]=(bf16_t)c.x; qk[1]=(bf16_t)c.y; qk[2]=(bf16_t)c.z; qk[3]=(bf16_t)c.w;
      *(bf16x4*)(XC + t * 136 + (i * 8 + qq) * 4) = qk;
    }
  }
  __syncthreads();

  const bf16_t* wsH = wsW + h * 10240;

  bf16x8 aK[4], bQ[4], aV[2];
  // ---- XV-derived: qv, kv, V (bias via C-init; per-ks X loads) ----
  {
    f32x4 qa[4], ka[4], va[4];
    {
      f32x4 initQ, initK, initV;
#pragma unroll
      for (int r = 0; r < 4; ++r) {
        const int ev = q * 4 + r;
        initQ[r] = 0.25f * bv[(ev * 8 + h) * 3 + 0];
        initK[r] = bv[(ev * 8 + h) * 3 + 1];
      }
      const float bvv = bv[(col16 * 8 + h) * 3 + 2];
      initV[0] = bvv; initV[1] = bvv; initV[2] = bvv; initV[3] = bvv;
#pragma unroll
      for (int t4 = 0; t4 < 4; ++t4) { qa[t4] = initQ; ka[t4] = initK; va[t4] = initV; }
    }
#pragma unroll
    for (int ks = 0; ks < 4; ++ks) {
      bf16x8 xk[4];
#pragma unroll
      for (int t4 = 0; t4 < 4; ++t4)
        xk[t4] = *(const bf16x8*)(XV + (t4 * 16 + col16) * 136 + ks * 32 + q * 8);
      bf16x8 wq = *(const bf16x8*)(wsH + (0  + ks) * 512 + l * 8);
      bf16x8 wk = *(const bf16x8*)(wsH + (4  + ks) * 512 + l * 8);
      bf16x8 wv = *(const bf16x8*)(wsH + (16 + ks) * 512 + l * 8);
#pragma unroll
      for (int t4 = 0; t4 < 4; ++t4) {
        qa[t4] = __builtin_amdgcn_mfma_f32_16x16x32_bf16(wq, xk[t4], qa[t4], 0, 0, 0);
        ka[t4] = __builtin_amdgcn_mfma_f32_16x16x32_bf16(wk, xk[t4], ka[t4], 0, 0, 0);
        va[t4] = __builtin_amdgcn_mfma_f32_16x16x32_bf16(xk[t4], wv, va[t4], 0, 0, 0);
      }
    }
    // pack V A-frags: slot(q,jj) -> token 16*(2*ks2+(jj>=4)) + 4q + (jj&3)
#pragma unroll
    for (int ks2 = 0; ks2 < 2; ++ks2)
#pragma unroll
      for (int jj = 0; jj < 8; ++jj)
        aV[ks2][jj] = (bf16_t)(va[2 * ks2 + (jj >> 2)][jj & 3]);
    // value halves of S^T operands (channel pi: slot r -> ch 4q+r)
#pragma unroll
    for (int m = 0; m < 4; ++m)
#pragma unroll
      for (int r = 0; r < 4; ++r) {
        aK[m][r] = (bf16_t)ka[m][r];
        bQ[m][r] = (bf16_t)qa[m][r];
      }
  }
  // ---- qc pass ----
  {
    f32x4 cacc[4];
    {
      f32x4 initQC;
#pragma unroll
      for (int r = 0; r < 4; ++r) initQC[r] = 0.25f * bc[((q * 4 + r) * 8 + h) * 2 + 0];
#pragma unroll
      for (int t4 = 0; t4 < 4; ++t4) cacc[t4] = initQC;
    }
#pragma unroll
    for (int ks = 0; ks < 4; ++ks) {
      bf16x8 xk[4];
#pragma unroll
      for (int t4 = 0; t4 < 4; ++t4)
        xk[t4] = *(const bf16x8*)(XC + (t4 * 16 + col16) * 136 + ks * 32 + q * 8);
      bf16x8 wq = *(const bf16x8*)(wsH + (8 + ks) * 512 + l * 8);
#pragma unroll
      for (int t4 = 0; t4 < 4; ++t4)
        cacc[t4] = __builtin_amdgcn_mfma_f32_16x16x32_bf16(wq, xk[t4], cacc[t4], 0, 0, 0);
    }
#pragma unroll
    for (int m = 0; m < 4; ++m)
#pragma unroll
      for (int r = 0; r < 4; ++r) bQ[m][4 + r] = (bf16_t)cacc[m][r];
  }
  // ---- kc pass (re-reads XC; keeps peak regs low) ----
  {
    f32x4 cacc[4];
    {
      f32x4 initKC;
#pragma unroll
      for (int r = 0; r < 4; ++r) initKC[r] = bc[((q * 4 + r) * 8 + h) * 2 + 1];
#pragma unroll
      for (int t4 = 0; t4 < 4; ++t4) cacc[t4] = initKC;
    }
#pragma unroll
    for (int ks = 0; ks < 4; ++ks) {
      bf16x8 xk[4];
#pragma unroll
      for (int t4 = 0; t4 < 4; ++t4)
        xk[t4] = *(const bf16x8*)(XC + (t4 * 16 + col16) * 136 + ks * 32 + q * 8);
      bf16x8 wk = *(const bf16x8*)(wsH + (12 + ks) * 512 + l * 8);
#pragma unroll
      for (int t4 = 0; t4 < 4; ++t4)
        cacc[t4] = __builtin_amdgcn_mfma_f32_16x16x32_bf16(wk, xk[t4], cacc[t4], 0, 0, 0);
    }
#pragma unroll
    for (int m = 0; m < 4; ++m)
#pragma unroll
      for (int r = 0; r < 4; ++r) aK[m][4 + r] = (bf16_t)cacc[m][r];
  }
  __syncthreads();   // all XV/XC reads done; XV region becomes Y

  // ---- attention, streamed per i-tile ni (S^T: lane col=i, regs=j) ----
#pragma unroll
  for (int ni = 0; ni < 4; ++ni) {
    const int i = ni * 16 + col16;
    const int pb = ((q >> 1) - (i >> 3) + 7) * 15 + ((q & 1) << 2) - (i & 7) + 7;
    f32x4 sv[4];
#pragma unroll
    for (int mj = 0; mj < 4; ++mj)
#pragma unroll
      for (int r = 0; r < 4; ++r)
        sv[mj][r] = POS[pb + mj * 30 + r];        // C-init = pos bias
#pragma unroll
    for (int mj = 0; mj < 4; ++mj)
      sv[mj] = __builtin_amdgcn_mfma_f32_16x16x32_bf16(aK[mj], bQ[ni], sv[mj], 0, 0, 0);
    if (lastRow) {
#pragma unroll
      for (int mj = 0; mj < 4; ++mj)
#pragma unroll
        for (int r = 0; r < 4; ++r)
          if ((i ^ (mj * 16 + q * 4 + r)) & 32) sv[mj][r] = -1e30f;
    }
    if (lastCol) {
#pragma unroll
      for (int mj = 0; mj < 4; ++mj)
#pragma unroll
        for (int r = 0; r < 4; ++r)
          if ((i ^ (mj * 16 + q * 4 + r)) & 4) sv[mj][r] = -1e30f;
    }
    float sum = 0.f;
#pragma unroll
    for (int mj = 0; mj < 4; ++mj)
#pragma unroll
      for (int r = 0; r < 4; ++r) {
        float e = __expf(sv[mj][r]);              // bounded inputs: no max-subtract
        sv[mj][r] = e;
        sum += e;
      }
    sum += __shfl_xor(sum, 16, 64);
    sum += __shfl_xor(sum, 32, 64);
    const float inv = __builtin_amdgcn_rcpf(sum);
    bf16x8 bP0, bP1;
#pragma unroll
    for (int jj = 0; jj < 8; ++jj) {
      bP0[jj] = (bf16_t)sv[(jj >> 2)][jj & 3];
      bP1[jj] = (bf16_t)sv[2 + (jj >> 2)][jj & 3];
    }
    const f32x4 zz = {0.f, 0.f, 0.f, 0.f};
    f32x4 o = __builtin_amdgcn_mfma_f32_16x16x32_bf16(aV[0], bP0, zz, 0, 0, 0);
    o = __builtin_amdgcn_mfma_f32_16x16x32_bf16(aV[1], bP1, o, 0, 0, 0);
    bf16x4 pk;
#pragma unroll
    for (int r = 0; r < 4; ++r) pk[r] = (bf16_t)(o[r] * inv);
    *(bf16x4*)(Y + i * 136 + h * 16 + q * 4) = pk;   // Y[token][h*16+e]
  }
  __syncthreads();

  // ---- phase 3: out^T = WoA . Y^T  (lane col=token, regs=o) ----
  {
    f32x4 acc[4] = {};
#pragma unroll
    for (int ks = 0; ks < 4; ++ks) {
      bf16x8 woA = *(const bf16x8*)(wsW + 81920 + (w * 4 + ks) * 512 + l * 8);
#pragma unroll
      for (int ni = 0; ni < 4; ++ni) {
        bf16x8 yf = *(const bf16x8*)(Y + (ni * 16 + col16) * 136 + ks * 32 + q * 8);
        acc[ni] = __builtin_amdgcn_mfma_f32_16x16x32_bf16(woA, yf, acc[ni], 0, 0, 0);
      }
    }
    const float4 bo4 = *(const float4*)(bo + w * 16 + q * 4);
    const int rg0 = wy << 3, cg0 = wx << 3;
#pragma unroll
    for (int ni = 0; ni < 4; ++ni) {
      const int t = ni * 16 + col16;
      const int rg = rg0 + (t >> 3), cg = cg0 + (t & 7);
      float4 st;
      st.x = acc[ni][0] + bo4.x;
      st.y = acc[ni][1] + bo4.y;
      st.z = acc[ni][2] + bo4.z;
      st.w = acc[ni][3] + bo4.w;
      *(float4*)(out + ((size_t)b * 65536 + (size_t)rg * 256 + (size_t)cg) * 128 +
                 w * 16 + q * 4) = st;
    }
  }
}

extern "C" void kernel_launch(void* const* d_in, const int* in_sizes, int n_in,
                              void* d_out, int out_size, void* d_ws, size_t ws_size,
                              hipStream_t stream) {
  const float* gxv = (const float*)d_in[0];
  const float* gxc = (const float*)d_in[1];
  const float* Wv  = (const float*)d_in[2];
  const float* bv  = (const float*)d_in[3];
  const float* Wc  = (const float*)d_in[4];
  const float* bc  = (const float*)d_in[5];
  const float* pe  = (const float*)d_in[6];
  const float* Wo  = (const float*)d_in[7];
  const float* bo  = (const float*)d_in[8];
  float* out = (float*)d_out;
  bf16_t* wsW = (bf16_t*)d_ws;   // 192KB fragment-ordered bf16 weights

  hipFuncSetAttribute((const void*)swin_fused_k,
                      hipFuncAttributeMaxDynamicSharedMemorySize, SMEM_BYTES);
  prep_weights_k<<<192, 512, 0, stream>>>(Wv, Wc, Wo, wsW);
  swin_fused_k<<<4096, 512, SMEM_BYTES, stream>>>(gxv, gxc, bv, bc, pe, bo, wsW, out);
}